// Round 5
// baseline (2574.255 us; speedup 1.0000x reference)
//
#include <hip/hip_runtime.h>

// Dims
constexpr int TSTEPS = 512;
constexpr int FDIM   = 128;
constexpr int HDIM   = 256;
constexpr int G4H    = 1024;   // 4*H
constexpr int TC     = 8;      // time-chunk (xz granularity)
constexpr int NCH    = TSTEPS / TC;

typedef float        f32x2 __attribute__((ext_vector_type(2)));
typedef _Float16     h2    __attribute__((ext_vector_type(2)));
typedef unsigned int u32;
typedef unsigned long long u64;
typedef u32          u32x2 __attribute__((ext_vector_type(2)));
typedef u32          u32x4 __attribute__((ext_vector_type(4)));

#if defined(__has_builtin)
#if __has_builtin(__builtin_amdgcn_fdot2)
#define FDOT2(a, b, c) __builtin_amdgcn_fdot2((a), (b), (c), false)
#endif
#endif
#ifndef FDOT2
#define FDOT2(a, b, c) ((c) + (float)(a)[0] * (float)(b)[0] + (float)(a)[1] * (float)(b)[1])
#endif

__device__ __forceinline__ h2 as_h2(u32 v) { union { u32 u; h2 p; } c; c.u = v; return c.p; }
__device__ __forceinline__ u32 pack_h2(float a, float b) {
    union { h2 p; u32 u; } c; c.p = h2{(_Float16)a, (_Float16)b}; return c.u;
}
__device__ __forceinline__ float sigmf(float z) { return 1.f / (1.f + __expf(-z)); }
__device__ __forceinline__ float tanhf_fast(float z) {
    float a = fabsf(z);
    float e = __expf(-2.f * a);
    float r = (1.f - e) / (1.f + e);
    return z < 0.f ? -r : r;
}

// ws layout (u32): [0],[1]=startup counters, [512..) WG = repacked rker
// (4 members x 32768 u32 = 512 KB). HX (65536 u64 = 512 KB) EXACTLY overlays
// WG — safe: WG fully consumed (loaded into per-thread VGPRs) before
// counter-barrier 1 (the preceding __syncthreads drains vmcnt(0)); HX tag
// slots zeroed before counter-barrier 2; only then does any block poll.
// HX entry = u64 { lo: h fp16 pair, hi: tag = t+1 } (tag+data one word).
//
// WG layout per member q: [kp(128)][u(64)][g4(4)] u32 = fp16 pair
// (rker[2kp][gcol], rker[2kp+1][gcol]), gcol = g4*256 + 64q + u.
//
// v5: W lives in REGISTERS. Thread (u = tid>>3, ks = tid&7) needs exactly
// W[kp=i*8+ks][u][g4], i<16, g4<4 -> u32x4 Wr[16] = 64 VGPRs, statically
// indexed in the fully-unrolled dot loop. This deletes the r4 kernel's
// per-step 128 KB/CU LDS W-stream (128 ds_read_b128/step) entirely; the
// dot's only LDS reads are 16 broadcast h-b128s with immediate offsets.
// Freed LDS is padded off (dynamic 72 KB at launch) so LDS/block stays
// >80 KB -> provably 1 block/CU -> the 256-block co-residency argument
// and per-CU perf layout are unchanged.

extern "C" __global__ void __launch_bounds__(256)
conv_wpk(const float* __restrict__ rker, u32* __restrict__ ws)
{
    for (int i = blockIdx.x * 256 + threadIdx.x; i < 512 + 4 * 32768; i += gridDim.x * 256) {
        if (i < 512) { ws[i] = 0; continue; }   // zero counters (every launch)
        const int ii = i - 512;
        const int q  = ii >> 15, j = ii & 32767;
        const int kp = j >> 8, rem = j & 255;
        const int u  = rem >> 2, g4 = rem & 3;
        const int gcol = g4 * 256 + 64 * q + u;
        const float a = rker[(size_t)(2 * kp) * G4H + gcol];
        const float b = rker[(size_t)(2 * kp + 1) * G4H + gcol];
        ws[i] = pack_h2(a, b);
    }
}

// xs XOR swizzle: word (fp*32 + rr*8 + tt) ^ ((fp&7)<<2). Keeps 16B alignment
// (bits 0-1 untouched); spreads the staging write 8-way.
__device__ __forceinline__ int xs_idx(int fp, int rr, int tt) {
    return (fp * 32 + rr * 8 + tt) ^ ((fp & 7) << 2);
}

extern "C" __global__ void __launch_bounds__(512)
lstm_pers(const float* __restrict__ x, const float* __restrict__ kern,
          u32* __restrict__ ws,
          const float* __restrict__ w1, const float* __restrict__ b1,
          const float* __restrict__ w2, const float* __restrict__ b2,
          float* __restrict__ out)
{
    const int bid = blockIdx.x;
    const int g   = bid & 63;        // group: rows [4g, 4g+4)
    const int q   = bid >> 6;        // member: units [64q, 64q+64)
    const int tid = threadIdx.x;

    const u32* const WG = ws + 512;
    u64*       const HX = (u64*)(ws + 512);  // overlays WG (guarded by barriers)

    // Static LDS: 16384 + 8192 + 4096 = 28,672 B; +72 KB dynamic pad at launch
    // => 102,400 B/block => 1 block/CU guaranteed.
    __shared__ __align__(16) u32 xzp[4096];    // xz fp16 row-pairs [rp][tc][c]
    __shared__ __align__(16) u32 xs[2048];     // x fp16 f-pairs, XOR-swizzled
    __shared__ __align__(16) u32 hpk2[1024];   // h fp16 pairs, 2 bufs x [kp][r]
    float* const hid = (float*)xs;             // head overlay (after final barrier)

    // Dot-phase mapping: thread = (u, ks); unit 64q+u, K-subset kp == i*8+ks
    const int u  = tid >> 3;
    const int ks = tid & 7;

    // ---- One-time: weights -> REGISTERS; h(0)=0; two global counter barriers
    u32x4 Wr[16];
#pragma unroll
    for (int i = 0; i < 16; ++i)
        Wr[i] = *reinterpret_cast<const u32x4*>(
            &WG[(size_t)q * 32768 + (size_t)(i * 8 + ks) * 256 + u * 4]);
    for (int i = tid; i < 1024; i += 512) hpk2[i] = 0;
    __syncthreads();  // drains vmcnt(0): all WG loads serviced before signalling
    if (tid == 0) {   // barrier 1: every block has consumed WG
        atomicAdd(&ws[0], 1u);
        while (__hip_atomic_load(&ws[0], __ATOMIC_RELAXED, __HIP_MEMORY_SCOPE_AGENT) < 256u) {}
    }
    __syncthreads();
    if (tid < 256) {  // zero OWN HX tag slots, both buffers
        const int bsel = tid >> 7, e = tid & 127;
        __hip_atomic_store(&HX[((size_t)(bsel * 64 + g) * 4 + q) * 128 + e], 0ull,
                           __ATOMIC_RELAXED, __HIP_MEMORY_SCOPE_AGENT);
    }
    __syncthreads();  // zero-stores drained (vmcnt(0) before s_barrier)
    if (tid == 0) {   // barrier 2: every block's tags are clean
        atomicAdd(&ws[1], 1u);
        while (__hip_atomic_load(&ws[1], __ATOMIC_RELAXED, __HIP_MEMORY_SCOPE_AGENT) < 256u) {}
    }
    __syncthreads();

    // Phase-A burst mapping (proven r1/r3): (c, half)
    const int bc    = tid & 255;
    const int bhalf = tid >> 8;
    const int bgcol = (bc >> 6) * 256 + 64 * q + (bc & 63);
    // Import mapping: tid in [128,512) -> (partner pp, entry ie)
    const int ik = tid - 128;
    const int pp = (ik >> 7) + ((ik >> 7) >= q);
    const int ie = ik & 127;
    float cst = 0.f;   // cell state: lanes ks<4 hold (unit u, row ks)

#pragma unroll 1
    for (int ch = 0; ch < NCH; ++ch) {
        __syncthreads();  // SA0: prev-chunk step reads of xzp/xs done

        // ---- Stage x chunk: xs (swizzled)
#pragma unroll
        for (int i = 0; i < 4; ++i) {
            const int slot = tid + i * 512;
            const int rt = slot >> 6, fp = slot & 63;
            const int rr = rt >> 3, tt = rt & 7;
            const f32x2 xv = *reinterpret_cast<const f32x2*>(
                &x[(((size_t)(4 * g + rr)) * TSTEPS + (ch * TC + tt)) * FDIM + 2 * fp]);
            xs[xs_idx(fp, rr, tt)] = pack_h2(xv[0], xv[1]);
        }
        __syncthreads();  // SA1: xs ready

        // ---- Phase A burst (identical math/order to r3/r4): xz -> xzp
        {
            float acc[4][4];  // [tp][row]
#pragma unroll
            for (int tp = 0; tp < 4; ++tp)
#pragma unroll
                for (int rr = 0; rr < 4; ++rr) acc[tp][rr] = 0.f;
#pragma unroll 4
            for (int fp = 0; fp < 64; ++fp) {
                const float k0 = kern[(size_t)(2 * fp) * G4H + bgcol];
                const float k1 = kern[(size_t)(2 * fp + 1) * G4H + bgcol];
                const h2 wp = h2{(_Float16)k0, (_Float16)k1};
#pragma unroll
                for (int rr = 0; rr < 4; ++rr) {
                    const u32x4 X = *reinterpret_cast<const u32x4*>(&xs[xs_idx(fp, rr, bhalf * 4)]);
#pragma unroll
                    for (int tp = 0; tp < 4; ++tp)
                        acc[tp][rr] = FDOT2(wp, as_h2(X[tp]), acc[tp][rr]);
                }
            }
#pragma unroll
            for (int tp = 0; tp < 4; ++tp)
#pragma unroll
                for (int rp = 0; rp < 2; ++rp)
                    xzp[rp * 2048 + (bhalf * 4 + tp) * 256 + bc] =
                        pack_h2(acc[tp][2 * rp], acc[tp][2 * rp + 1]);
        }

        // ---- Phase B: 8 steps; ONE barrier per step
#pragma unroll 1
        for (int tc = 0; tc < TC; ++tc) {
            const int t    = ch * TC + tc;
            const int bufC = t & 1, bufN = bufC ^ 1;
            __syncthreads();  // B1: hpk2[bufC] complete; xzp(ch) ready

            // Dot: acc[g][r] for unit u over this lane's 16 kp.
            // W from registers (Wr, static index); h via 16 broadcast b128s
            // at immediate offsets off one per-thread base.
            float acc[4][4];
#pragma unroll
            for (int gg = 0; gg < 4; ++gg)
#pragma unroll
                for (int rr = 0; rr < 4; ++rr) acc[gg][rr] = 0.f;
#pragma unroll
            for (int i = 0; i < 16; ++i) {
                const u32x4 Hh = *reinterpret_cast<const u32x4*>(
                    &hpk2[bufC * 512 + (i * 8 + ks) * 4]);
                const u32x4 W = Wr[i];
#pragma unroll
                for (int gg = 0; gg < 4; ++gg) {
                    const h2 wg = as_h2(W[gg]);
                    acc[gg][0] = FDOT2(wg, as_h2(Hh[0]), acc[gg][0]);
                    acc[gg][1] = FDOT2(wg, as_h2(Hh[1]), acc[gg][1]);
                    acc[gg][2] = FDOT2(wg, as_h2(Hh[2]), acc[gg][2]);
                    acc[gg][3] = FDOT2(wg, as_h2(Hh[3]), acc[gg][3]);
                }
            }

            // Reduce-scatter over ks (3 rounds): row r=ks lands in lanes ks<4
            const bool kb0 = (ks & 1), kb1 = (ks & 2);
            float v0[4], v1[4];
#pragma unroll
            for (int gg = 0; gg < 4; ++gg) {
                const float give0 = kb0 ? acc[gg][0] : acc[gg][1];
                const float give1 = kb0 ? acc[gg][2] : acc[gg][3];
                const float got0 = __shfl_xor(give0, 1);
                const float got1 = __shfl_xor(give1, 1);
                v0[gg] = (kb0 ? acc[gg][1] : acc[gg][0]) + got0;
                v1[gg] = (kb0 ? acc[gg][3] : acc[gg][2]) + got1;
            }
            float w4[4];
#pragma unroll
            for (int gg = 0; gg < 4; ++gg) {
                const float give = kb1 ? v0[gg] : v1[gg];
                const float got  = __shfl_xor(give, 2);
                w4[gg] = (kb1 ? v1[gg] : v0[gg]) + got;
            }
#pragma unroll
            for (int gg = 0; gg < 4; ++gg) w4[gg] += __shfl_xor(w4[gg], 4);

            if (ks < 4) {  // gate + export IMMEDIATELY; row r = ks
                const int r = ks;
                float z[4];
#pragma unroll
                for (int g4 = 0; g4 < 4; ++g4) {
                    const h2 xp = as_h2(xzp[(r >> 1) * 2048 + tc * 256 + g4 * 64 + u]);
                    z[g4] = w4[g4] + (float)((r & 1) ? xp[1] : xp[0]);
                }
                cst = sigmf(z[1]) * cst + sigmf(z[0]) * tanhf_fast(z[2]);
                const float hn = sigmf(z[3]) * tanhf_fast(cst);
                const float ho = __shfl_xor(hn, 8);  // unit u^1, same (ks=r)
                if (!(u & 1)) {
                    const int kpo = 32 * q + (u >> 1);
                    const u32 hv  = pack_h2(hn, ho);
                    hpk2[bufN * 512 + kpo * 4 + r] = hv;  // own slice, local
                    const int e = (u >> 1) * 4 + r;
                    __hip_atomic_store(&HX[((size_t)(bufN * 64 + g) * 4 + q) * 128 + e],
                                       ((u64)(u32)(t + 1) << 32) | (u64)hv,
                                       __ATOMIC_RELAXED, __HIP_MEMORY_SCOPE_AGENT);
                }
            }
            if (tid >= 128) {  // import: poll tag-in-word, then LDS write (stride-1)
                const u64* src = &HX[((size_t)(bufN * 64 + g) * 4 + pp) * 128 + ie];
                u64 v;
                do {
                    v = __hip_atomic_load(src, __ATOMIC_RELAXED, __HIP_MEMORY_SCOPE_AGENT);
                } while ((u32)(v >> 32) < (u32)(t + 1));
                hpk2[bufN * 512 + 128 * pp + ie] = (u32)v;
            }
            // next B1 orders hpk2[bufN] writes vs reads
        }
    }
    __syncthreads();  // h(512) complete in hpk2 buf 0

    // ---- Fused head: member q emits out[4g+q] using ROW q of the group's h
    if (tid < 100) {
        float aa = b1[tid];
        const _Float16* hph = (const _Float16*)hpk2;  // buf 0: [kp][r] pairs
#pragma unroll 8
        for (int k = 0; k < HDIM; ++k)
            aa += (float)hph[((k >> 1) * 4 + q) * 2 + (k & 1)] * w1[k * 100 + tid];
        hid[tid] = fmaxf(aa, 0.f);
    }
    __syncthreads();
    if (tid == 0) {
        float v = b2[0];
#pragma unroll 4
        for (int j = 0; j < 100; ++j) v += hid[j] * w2[j];
        out[4 * g + q] = v;
    }
}

extern "C" void kernel_launch(void* const* d_in, const int* in_sizes, int n_in,
                              void* d_out, int out_size, void* d_ws, size_t ws_size,
                              hipStream_t stream)
{
    const float* x    = (const float*)d_in[0];
    const float* kern = (const float*)d_in[1];
    const float* rker = (const float*)d_in[2];
    const float* w1   = (const float*)d_in[3];
    const float* b1   = (const float*)d_in[4];
    const float* w2   = (const float*)d_in[5];
    const float* b2   = (const float*)d_in[6];
    u32* ws = (u32*)d_ws;  // 2 KB hdr + 512 KB (WG/HX overlay) < 768 KB proven

    conv_wpk<<<dim3(514), dim3(256), 0, stream>>>(rker, ws);
    // 72 KB dynamic LDS pad: total 102,400 B/block => provably 1 block/CU.
    lstm_pers<<<dim3(256), dim3(512), 73728, stream>>>(x, kern, ws, w1, b1, w2, b2,
                                                       (float*)d_out);
}

// Round 6
// 2031.862 us; speedup vs baseline: 1.2669x; 1.2669x over previous
//
#include <hip/hip_runtime.h>

// Dims
constexpr int TSTEPS = 512;
constexpr int FDIM   = 128;
constexpr int HDIM   = 256;
constexpr int G4H    = 1024;   // 4*H
constexpr int TC     = 8;      // time-chunk (xz granularity)
constexpr int NCH    = TSTEPS / TC;

typedef float        f32x2 __attribute__((ext_vector_type(2)));
typedef _Float16     h2    __attribute__((ext_vector_type(2)));
typedef unsigned int u32;
typedef unsigned long long u64;
typedef u32          u32x2 __attribute__((ext_vector_type(2)));
typedef u32          u32x4 __attribute__((ext_vector_type(4)));

#if defined(__has_builtin)
#if __has_builtin(__builtin_amdgcn_fdot2)
#define FDOT2(a, b, c) __builtin_amdgcn_fdot2((a), (b), (c), false)
#endif
#endif
#ifndef FDOT2
#define FDOT2(a, b, c) ((c) + (float)(a)[0] * (float)(b)[0] + (float)(a)[1] * (float)(b)[1])
#endif

__device__ __forceinline__ h2 as_h2(u32 v) { union { u32 u; h2 p; } c; c.u = v; return c.p; }
__device__ __forceinline__ u32 pack_h2(float a, float b) {
    union { h2 p; u32 u; } c; c.p = h2{(_Float16)a, (_Float16)b}; return c.u;
}
__device__ __forceinline__ float sigmf(float z) { return 1.f / (1.f + __expf(-z)); }
__device__ __forceinline__ float tanhf_fast(float z) {
    float a = fabsf(z);
    float e = __expf(-2.f * a);
    float r = (1.f - e) / (1.f + e);
    return z < 0.f ? -r : r;
}

// ws layout (u32): [0],[1]=startup counters, [512..) WG = repacked rker
// (4 members x 32768 u32 = 512 KB). HX (65536 u64 = 512 KB) EXACTLY overlays
// WG — safe: WG fully consumed (loaded into per-thread VGPRs) before
// counter-barrier 1 (the preceding __syncthreads drains vmcnt(0)); HX tag
// slots zeroed before counter-barrier 2; only then does any block poll.
// HX entry = u64 { lo: h fp16 pair, hi: tag = t+1 } (tag+data one word).
//
// WG layout per member q: [kp(128)][u(64)][g4(4)] u32 = fp16 pair
// (rker[2kp][gcol], rker[2kp+1][gcol]), gcol = g4*256 + 64q + u.
//
// v6 = v5 with the register-budget signaling FIXED (r5 post-mortem):
// r5 hid the occupancy pad in dynamic LDS -> compiler (seeing 28 KB static)
// targeted 5 blocks/CU occupancy, minimized to 60 VGPR, and spilled Wr[16]
// to AGPR/scratch -> per-step reload tax (dur 2281->2574, VALUBusy 55->46,
// though bank-conflicts fell 18x proving the W-stream removal works).
// Fix: (a) pad is STATIC __shared__ (102,400 B total -> compiler knows
// 1 block/CU) and genuinely used (head 'hid' buffer lives in it);
// (b) __launch_bounds__(512, 2) -> min 2 waves/EU -> VGPR cap 256, no
// tighter. Wr[16] (64 VGPR) must now stay register-resident: the check
// is VGPR_Count ~140-200 in the trace.

extern "C" __global__ void __launch_bounds__(256)
conv_wpk(const float* __restrict__ rker, u32* __restrict__ ws)
{
    for (int i = blockIdx.x * 256 + threadIdx.x; i < 512 + 4 * 32768; i += gridDim.x * 256) {
        if (i < 512) { ws[i] = 0; continue; }   // zero counters (every launch)
        const int ii = i - 512;
        const int q  = ii >> 15, j = ii & 32767;
        const int kp = j >> 8, rem = j & 255;
        const int u  = rem >> 2, g4 = rem & 3;
        const int gcol = g4 * 256 + 64 * q + u;
        const float a = rker[(size_t)(2 * kp) * G4H + gcol];
        const float b = rker[(size_t)(2 * kp + 1) * G4H + gcol];
        ws[i] = pack_h2(a, b);
    }
}

// xs XOR swizzle: word (fp*32 + rr*8 + tt) ^ ((fp&7)<<2). Keeps 16B alignment
// (bits 0-1 untouched); spreads the staging write 8-way.
__device__ __forceinline__ int xs_idx(int fp, int rr, int tt) {
    return (fp * 32 + rr * 8 + tt) ^ ((fp & 7) << 2);
}

extern "C" __global__ void __launch_bounds__(512, 2)
lstm_pers(const float* __restrict__ x, const float* __restrict__ kern,
          u32* __restrict__ ws,
          const float* __restrict__ w1, const float* __restrict__ b1,
          const float* __restrict__ w2, const float* __restrict__ b2,
          float* __restrict__ out)
{
    const int bid = blockIdx.x;
    const int g   = bid & 63;        // group: rows [4g, 4g+4)
    const int q   = bid >> 6;        // member: units [64q, 64q+64)
    const int tid = threadIdx.x;

    const u32* const WG = ws + 512;
    u64*       const HX = (u64*)(ws + 512);  // overlays WG (guarded by barriers)

    // Static LDS: 16384 + 8192 + 4096 + 73728 = 102,400 B => compiler-visible
    // 1 block/CU (the point of the pad being STATIC — see v6 header note).
    __shared__ __align__(16) u32 xzp[4096];    // xz fp16 row-pairs [rp][tc][c]
    __shared__ __align__(16) u32 xs[2048];     // x fp16 f-pairs, XOR-swizzled
    __shared__ __align__(16) u32 hpk2[1024];   // h fp16 pairs, 2 bufs x [kp][r]
    __shared__ __align__(16) u32 pad[18432];   // occupancy pad; head 'hid' lives here
    float* const hid = (float*)pad;            // genuinely used -> pad not DCE'd

    // Dot-phase mapping: thread = (u, ks); unit 64q+u, K-subset kp == i*8+ks
    const int u  = tid >> 3;
    const int ks = tid & 7;

    // ---- One-time: weights -> REGISTERS; h(0)=0; two global counter barriers
    u32x4 Wr[16];
#pragma unroll
    for (int i = 0; i < 16; ++i)
        Wr[i] = *reinterpret_cast<const u32x4*>(
            &WG[(size_t)q * 32768 + (size_t)(i * 8 + ks) * 256 + u * 4]);
    for (int i = tid; i < 1024; i += 512) hpk2[i] = 0;
    __syncthreads();  // drains vmcnt(0): all WG loads serviced before signalling
    if (tid == 0) {   // barrier 1: every block has consumed WG
        atomicAdd(&ws[0], 1u);
        while (__hip_atomic_load(&ws[0], __ATOMIC_RELAXED, __HIP_MEMORY_SCOPE_AGENT) < 256u) {}
    }
    __syncthreads();
    if (tid < 256) {  // zero OWN HX tag slots, both buffers
        const int bsel = tid >> 7, e = tid & 127;
        __hip_atomic_store(&HX[((size_t)(bsel * 64 + g) * 4 + q) * 128 + e], 0ull,
                           __ATOMIC_RELAXED, __HIP_MEMORY_SCOPE_AGENT);
    }
    __syncthreads();  // zero-stores drained (vmcnt(0) before s_barrier)
    if (tid == 0) {   // barrier 2: every block's tags are clean
        atomicAdd(&ws[1], 1u);
        while (__hip_atomic_load(&ws[1], __ATOMIC_RELAXED, __HIP_MEMORY_SCOPE_AGENT) < 256u) {}
    }
    __syncthreads();

    // Phase-A burst mapping (proven r1/r3): (c, half)
    const int bc    = tid & 255;
    const int bhalf = tid >> 8;
    const int bgcol = (bc >> 6) * 256 + 64 * q + (bc & 63);
    // Import mapping: tid in [128,512) -> (partner pp, entry ie)
    const int ik = tid - 128;
    const int pp = (ik >> 7) + ((ik >> 7) >= q);
    const int ie = ik & 127;
    float cst = 0.f;   // cell state: lanes ks<4 hold (unit u, row ks)

#pragma unroll 1
    for (int ch = 0; ch < NCH; ++ch) {
        __syncthreads();  // SA0: prev-chunk step reads of xzp/xs done

        // ---- Stage x chunk: xs (swizzled)
#pragma unroll
        for (int i = 0; i < 4; ++i) {
            const int slot = tid + i * 512;
            const int rt = slot >> 6, fp = slot & 63;
            const int rr = rt >> 3, tt = rt & 7;
            const f32x2 xv = *reinterpret_cast<const f32x2*>(
                &x[(((size_t)(4 * g + rr)) * TSTEPS + (ch * TC + tt)) * FDIM + 2 * fp]);
            xs[xs_idx(fp, rr, tt)] = pack_h2(xv[0], xv[1]);
        }
        __syncthreads();  // SA1: xs ready

        // ---- Phase A burst (identical math/order to r3/r4): xz -> xzp
        {
            float acc[4][4];  // [tp][row]
#pragma unroll
            for (int tp = 0; tp < 4; ++tp)
#pragma unroll
                for (int rr = 0; rr < 4; ++rr) acc[tp][rr] = 0.f;
#pragma unroll 4
            for (int fp = 0; fp < 64; ++fp) {
                const float k0 = kern[(size_t)(2 * fp) * G4H + bgcol];
                const float k1 = kern[(size_t)(2 * fp + 1) * G4H + bgcol];
                const h2 wp = h2{(_Float16)k0, (_Float16)k1};
#pragma unroll
                for (int rr = 0; rr < 4; ++rr) {
                    const u32x4 X = *reinterpret_cast<const u32x4*>(&xs[xs_idx(fp, rr, bhalf * 4)]);
#pragma unroll
                    for (int tp = 0; tp < 4; ++tp)
                        acc[tp][rr] = FDOT2(wp, as_h2(X[tp]), acc[tp][rr]);
                }
            }
#pragma unroll
            for (int tp = 0; tp < 4; ++tp)
#pragma unroll
                for (int rp = 0; rp < 2; ++rp)
                    xzp[rp * 2048 + (bhalf * 4 + tp) * 256 + bc] =
                        pack_h2(acc[tp][2 * rp], acc[tp][2 * rp + 1]);
        }

        // ---- Phase B: 8 steps; ONE barrier per step
#pragma unroll 1
        for (int tc = 0; tc < TC; ++tc) {
            const int t    = ch * TC + tc;
            const int bufC = t & 1, bufN = bufC ^ 1;
            __syncthreads();  // B1: hpk2[bufC] complete; xzp(ch) ready

            // Dot: acc[g][r] for unit u over this lane's 16 kp.
            // W from registers (Wr, static index); h via 16 broadcast b128s
            // at immediate offsets off one per-thread base.
            float acc[4][4];
#pragma unroll
            for (int gg = 0; gg < 4; ++gg)
#pragma unroll
                for (int rr = 0; rr < 4; ++rr) acc[gg][rr] = 0.f;
#pragma unroll
            for (int i = 0; i < 16; ++i) {
                const u32x4 Hh = *reinterpret_cast<const u32x4*>(
                    &hpk2[bufC * 512 + (i * 8 + ks) * 4]);
                const u32x4 W = Wr[i];
#pragma unroll
                for (int gg = 0; gg < 4; ++gg) {
                    const h2 wg = as_h2(W[gg]);
                    acc[gg][0] = FDOT2(wg, as_h2(Hh[0]), acc[gg][0]);
                    acc[gg][1] = FDOT2(wg, as_h2(Hh[1]), acc[gg][1]);
                    acc[gg][2] = FDOT2(wg, as_h2(Hh[2]), acc[gg][2]);
                    acc[gg][3] = FDOT2(wg, as_h2(Hh[3]), acc[gg][3]);
                }
            }

            // Reduce-scatter over ks (3 rounds): row r=ks lands in lanes ks<4
            const bool kb0 = (ks & 1), kb1 = (ks & 2);
            float v0[4], v1[4];
#pragma unroll
            for (int gg = 0; gg < 4; ++gg) {
                const float give0 = kb0 ? acc[gg][0] : acc[gg][1];
                const float give1 = kb0 ? acc[gg][2] : acc[gg][3];
                const float got0 = __shfl_xor(give0, 1);
                const float got1 = __shfl_xor(give1, 1);
                v0[gg] = (kb0 ? acc[gg][1] : acc[gg][0]) + got0;
                v1[gg] = (kb0 ? acc[gg][3] : acc[gg][2]) + got1;
            }
            float w4[4];
#pragma unroll
            for (int gg = 0; gg < 4; ++gg) {
                const float give = kb1 ? v0[gg] : v1[gg];
                const float got  = __shfl_xor(give, 2);
                w4[gg] = (kb1 ? v1[gg] : v0[gg]) + got;
            }
#pragma unroll
            for (int gg = 0; gg < 4; ++gg) w4[gg] += __shfl_xor(w4[gg], 4);

            if (ks < 4) {  // gate + export IMMEDIATELY; row r = ks
                const int r = ks;
                float z[4];
#pragma unroll
                for (int g4 = 0; g4 < 4; ++g4) {
                    const h2 xp = as_h2(xzp[(r >> 1) * 2048 + tc * 256 + g4 * 64 + u]);
                    z[g4] = w4[g4] + (float)((r & 1) ? xp[1] : xp[0]);
                }
                cst = sigmf(z[1]) * cst + sigmf(z[0]) * tanhf_fast(z[2]);
                const float hn = sigmf(z[3]) * tanhf_fast(cst);
                const float ho = __shfl_xor(hn, 8);  // unit u^1, same (ks=r)
                if (!(u & 1)) {
                    const int kpo = 32 * q + (u >> 1);
                    const u32 hv  = pack_h2(hn, ho);
                    hpk2[bufN * 512 + kpo * 4 + r] = hv;  // own slice, local
                    const int e = (u >> 1) * 4 + r;
                    __hip_atomic_store(&HX[((size_t)(bufN * 64 + g) * 4 + q) * 128 + e],
                                       ((u64)(u32)(t + 1) << 32) | (u64)hv,
                                       __ATOMIC_RELAXED, __HIP_MEMORY_SCOPE_AGENT);
                }
            }
            if (tid >= 128) {  // import: poll tag-in-word, then LDS write (stride-1)
                const u64* src = &HX[((size_t)(bufN * 64 + g) * 4 + pp) * 128 + ie];
                u64 v;
                do {
                    v = __hip_atomic_load(src, __ATOMIC_RELAXED, __HIP_MEMORY_SCOPE_AGENT);
                } while ((u32)(v >> 32) < (u32)(t + 1));
                hpk2[bufN * 512 + 128 * pp + ie] = (u32)v;
            }
            // next B1 orders hpk2[bufN] writes vs reads
        }
    }
    __syncthreads();  // h(512) complete in hpk2 buf 0

    // ---- Fused head: member q emits out[4g+q] using ROW q of the group's h
    if (tid < 100) {
        float aa = b1[tid];
        const _Float16* hph = (const _Float16*)hpk2;  // buf 0: [kp][r] pairs
#pragma unroll 8
        for (int k = 0; k < HDIM; ++k)
            aa += (float)hph[((k >> 1) * 4 + q) * 2 + (k & 1)] * w1[k * 100 + tid];
        hid[tid] = fmaxf(aa, 0.f);
    }
    __syncthreads();
    if (tid == 0) {
        float v = b2[0];
#pragma unroll 4
        for (int j = 0; j < 100; ++j) v += hid[j] * w2[j];
        out[4 * g + q] = v;
    }
}

extern "C" void kernel_launch(void* const* d_in, const int* in_sizes, int n_in,
                              void* d_out, int out_size, void* d_ws, size_t ws_size,
                              hipStream_t stream)
{
    const float* x    = (const float*)d_in[0];
    const float* kern = (const float*)d_in[1];
    const float* rker = (const float*)d_in[2];
    const float* w1   = (const float*)d_in[3];
    const float* b1   = (const float*)d_in[4];
    const float* w2   = (const float*)d_in[5];
    const float* b2   = (const float*)d_in[6];
    u32* ws = (u32*)d_ws;  // 2 KB hdr + 512 KB (WG/HX overlay) < 768 KB proven

    conv_wpk<<<dim3(514), dim3(256), 0, stream>>>(rker, ws);
    lstm_pers<<<dim3(256), dim3(512), 0, stream>>>(x, kern, ws, w1, b1, w2, b2,
                                                   (float*)d_out);
}